// Round 6
// baseline (244.236 us; speedup 1.0000x reference)
//
#include <hip/hip_runtime.h>
#include <stdint.h>

// VectorQuantizer — bit-exact replication of the fp32 numpy reference.
//   d = sum(z*z,1)[:,None] + sum(c*c,1)[None,:] - 2.0*einsum('nc,kc->nk',z,c)
// sums: numpy pairwise_sum n=64 (8 accumulators + fixed tree). einsum: AVX512
// order — 16 chained-FMA lanes over 4 blocks of 16, then reduce_add tree.
//
// Round 6 theory: r0-r5 all pinned at 137-155us with VALUBusy ~65% (busy
// ~90us vs 71us essential floor, stall ~48us). The stall is structural to
// the scalar-load row fetch: s_load returns decrement lgkmcnt OUT OF ORDER,
// so the compiler can only use lgkmcnt(0) full-drain waits — row k+1 cannot
// be issued past row k's wait, scalar fetch is un-pipelineable, and the
// only cover (TLP) is capped at ~3-4 waves/SIMD and correlated by drafting.
// Fix: codebook in LDS (128KB of gfx950's 160KB; AITER uses 160KB blocks).
// ds_read broadcasts (uniform addr = conflict-free) and the compiler emits
// COUNTED lgkmcnt(N) for ds_read consumers -> next row's reads overlap this
// row's FMAs; staging is once per block, not per iteration.
//
// Structure: 512-thread blocks = 2 point-groups x 4-wave k-split; 128 pts
// per block, 1024 blocks, 8192 waves. Codebook + cnorm staged to LDS once.
// Inner loop: 16x ds_read_b128 (row) + scalar-fmaf chains (proven sequence).
// Fallback (if >64KB dynamic LDS attr refused): the proven r5 s_load kernel.
// Argmin: ascending disjoint k-ranges, strict < (first occurrence), combine
// over ranges in ascending order.

#pragma clang fp contract(off)

#define KCODES 512
#define CDIM 64
#define HW 4096              // 64*64
#define ZQ_ELEMS 8388608     // 32*64*64*64

// dynamic LDS layout (float index):
//   [0, 32768)        codebook 512x64
//   [32768, 33280)    cnorm[512]
//   [33280, 33792)    dcand [2 pgrp][4 rng][64]
//   [33792, 34304)    kcand [2 pgrp][4 rng][64]  (int)
//   [34304, 34432)    kbest [128]                (int)
#define LDS_FLOATS 34432
#define LDS_BYTES  (LDS_FLOATS * 4)

// np.sum(row*row): pairwise_sum n=64 replica (products pre-rounded), one row
static __device__ __forceinline__ float cnorm_row(const float* __restrict__ row) {
    float r[8];
    #pragma unroll
    for (int j = 0; j < 8; ++j) r[j] = row[j] * row[j];
    #pragma unroll
    for (int i = 8; i < 64; i += 8) {
        #pragma unroll
        for (int j = 0; j < 8; ++j) r[j] = r[j] + row[i + j] * row[i + j];
    }
    return ((r[0] + r[1]) + (r[2] + r[3])) + ((r[4] + r[5]) + (r[6] + r[7]));
}

// One-shot: cnorm[512] into workspace. 2 blocks x 256 threads.
__global__ void cnorm_kernel(const float* __restrict__ cb,
                             float* __restrict__ cnorm_out) {
    int k = (int)blockIdx.x * 256 + (int)threadIdx.x;
    if (k < KCODES) cnorm_out[k] = cnorm_row(cb + (size_t)k * CDIM);
}

// ---------------- LDS-codebook kernel (primary path) ----------------
__global__ __launch_bounds__(512)
void vq_lds(const float* __restrict__ z_e,
            const float* __restrict__ cb,
            const float* __restrict__ cnorm_g,   // precomputed (d_ws) or nullptr
            float* __restrict__ out)
{
    extern __shared__ float smem[];
    float* cbs   = smem;                    // 32768 floats
    float* cnorm = smem + 32768;            // 512
    float* dcand = smem + 33280;            // 512
    int*   kcand = (int*)(smem + 33792);    // 512
    int*   kbest = (int*)(smem + 34304);    // 128

    const int tid = (int)threadIdx.x;

    // stage codebook: 512 threads x 16 float4 = 128KB, coalesced, bitwise copy
    {
        const float4* src = (const float4*)cb;
        float4* dst = (float4*)cbs;
        #pragma unroll
        for (int j = 0; j < 16; ++j)
            dst[tid + 512 * j] = src[tid + 512 * j];
    }
    if (cnorm_g) {
        if (tid < KCODES) cnorm[tid] = cnorm_g[tid];
    } else {
        if (tid < KCODES) cnorm[tid] = cnorm_row(cb + (size_t)tid * CDIM);
    }

    // wave decomposition: 8 waves = 2 point-groups x 4 k-ranges
    const int lane = tid & 63;
    const int wid  = __builtin_amdgcn_readfirstlane(tid >> 6);
    const int g    = wid & 3;        // k-range
    const int pgrp = wid >> 2;       // point group (0: pts 0-63, 1: 64-127)

    const int n0 = (int)blockIdx.x * 128;      // 128 | HW -> single image
    const int b = n0 / HW;
    const int hw0 = n0 % HW;
    const float* zp = z_e + (size_t)b * CDIM * HW + hw0 + pgrp * 64 + lane;

    // one point per lane: zz[m] = z[channel m]; coalesced 256B loads
    float zz[CDIM];
    #pragma unroll
    for (int m = 0; m < CDIM; ++m)
        zz[m] = zp[(size_t)m * HW];

    // np.sum(z*z, axis=1): pairwise replica (products pre-rounded)
    float sz;
    {
        float r[8];
        #pragma unroll
        for (int j = 0; j < 8; ++j) r[j] = zz[j] * zz[j];
        #pragma unroll
        for (int i = 8; i < 64; i += 8) {
            #pragma unroll
            for (int j = 0; j < 8; ++j) r[j] = r[j] + zz[i + j] * zz[i + j];
        }
        sz = ((r[0] + r[1]) + (r[2] + r[3])) + ((r[4] + r[5]) + (r[6] + r[7]));
    }

    __syncthreads();   // codebook + cnorm staged

    float best = 3.4e38f;
    int bk = 0;
    const int k0 = g * 128;

    #pragma unroll 2   // allow row double-buffering across iterations
    for (int i = 0; i < 128; ++i) {
        const int k = k0 + i;
        const float4* ck4 = (const float4*)(cbs + (size_t)k * CDIM);

        // row k from LDS: 16x ds_read_b128, wave-uniform addr (broadcast)
        float r[CDIM];
        #pragma unroll
        for (int j = 0; j < 16; ++j) {
            float4 t = ck4[j];
            r[4 * j + 0] = t.x; r[4 * j + 1] = t.y;
            r[4 * j + 2] = t.z; r[4 * j + 3] = t.w;
        }

        // einsum AVX512 order: 16 chained-FMA lanes over 4 blocks of 16
        float v[16];
        #pragma unroll
        for (int l = 0; l < 16; ++l)
            v[l] = fmaf(zz[l], r[l],
                     fmaf(zz[16 + l], r[16 + l],
                       fmaf(zz[32 + l], r[32 + l],
                         fmaf(zz[48 + l], r[48 + l], 0.f))));

        // reduce_add tree: e[l]=v[l]+v[8+l]; f[l]=e[l]+e[4+l];
        // dot = (f0+f2) + (f1+f3)
        float e[8];
        #pragma unroll
        for (int l = 0; l < 8; ++l) e[l] = v[l] + v[8 + l];
        float f[4];
        #pragma unroll
        for (int l = 0; l < 4; ++l) f[l] = e[l] + e[4 + l];
        float g0 = f[0] + f[2];
        float g1 = f[1] + f[3];
        float dot = g0 + g1;

        float A = sz + cnorm[k];               // fl(sz + sc_k)
        float d = fmaf(dot, -2.f, A);          // == fl(A - 2*dot): 2*dot exact

        if (d < best) { best = d; bk = k; }    // strict <: first occurrence
    }

    dcand[pgrp * 256 + g * 64 + lane] = best;
    kcand[pgrp * 256 + g * 64 + lane] = bk;
    __syncthreads();

    // combine over ascending k-ranges (strict < keeps first occurrence)
    if (tid < 128) {
        const int pg = tid >> 6, l = tid & 63;
        float bd = dcand[pg * 256 + l];
        int bi = kcand[pg * 256 + l];
        #pragma unroll
        for (int gg = 1; gg < 4; ++gg) {
            float d2 = dcand[pg * 256 + gg * 64 + l];
            int   k2 = kcand[pg * 256 + gg * 64 + l];
            if (d2 < bd) { bd = d2; bi = k2; }
        }
        out[ZQ_ELEMS + n0 + tid] = (float)bi;  // indices (as float32)
        kbest[tid] = bi;
    }
    __syncthreads();

    // z_q: wave (pgrp,g) writes channels [16g,16g+16) for its 64 points
    const int bi = kbest[pgrp * 64 + lane];
    const float* row = cbs + (size_t)bi * CDIM;   // LDS gather
    float* op = out + (size_t)b * CDIM * HW + hw0 + pgrp * 64 + lane;
    #pragma unroll
    for (int c = 0; c < 16; ++c) {
        const int ch = g * 16 + c;
        op[(size_t)ch * HW] = row[ch];
    }
}

// ---------------- s_load fallback (proven r5 kernel, 137us) ----------------
__global__ __launch_bounds__(256)
void vq_sload(const float* __restrict__ z_e,
              const float* __restrict__ cb,
              const float* __restrict__ cnorm_g,
              float* __restrict__ out)
{
    __shared__ float cnorm[KCODES];
    __shared__ float dcand[4 * 64];
    __shared__ int   kcand[4 * 64];

    if (cnorm_g) {
        #pragma unroll
        for (int k = (int)threadIdx.x; k < KCODES; k += 256)
            cnorm[k] = cnorm_g[k];
    } else {
        for (int k = (int)threadIdx.x; k < KCODES; k += 256)
            cnorm[k] = cnorm_row(cb + (size_t)k * CDIM);
    }

    const int lane = (int)threadIdx.x & 63;
    const int g = __builtin_amdgcn_readfirstlane((int)threadIdx.x >> 6);
    const int n0 = (int)blockIdx.x * 64;
    const int b = n0 / HW;
    const int hw0 = n0 % HW;
    const float* zp = z_e + (size_t)b * CDIM * HW + hw0 + lane;

    float zz[CDIM];
    #pragma unroll
    for (int m = 0; m < CDIM; ++m)
        zz[m] = zp[(size_t)m * HW];

    float sz;
    {
        float r[8];
        #pragma unroll
        for (int j = 0; j < 8; ++j) r[j] = zz[j] * zz[j];
        #pragma unroll
        for (int i = 8; i < 64; i += 8) {
            #pragma unroll
            for (int j = 0; j < 8; ++j) r[j] = r[j] + zz[i + j] * zz[i + j];
        }
        sz = ((r[0] + r[1]) + (r[2] + r[3])) + ((r[4] + r[5]) + (r[6] + r[7]));
    }

    __syncthreads();

    float best = 3.4e38f;
    int bk = 0;
    const int k0 = g * 128;

    for (int i = 0; i < 128; ++i) {
        const int k = k0 + i;
        const float* ck = cb + (size_t)k * CDIM;

        float v[16];
        #pragma unroll
        for (int l = 0; l < 16; ++l)
            v[l] = fmaf(zz[l], ck[l],
                     fmaf(zz[16 + l], ck[16 + l],
                       fmaf(zz[32 + l], ck[32 + l],
                         fmaf(zz[48 + l], ck[48 + l], 0.f))));

        float e[8];
        #pragma unroll
        for (int l = 0; l < 8; ++l) e[l] = v[l] + v[8 + l];
        float f[4];
        #pragma unroll
        for (int l = 0; l < 4; ++l) f[l] = e[l] + e[4 + l];
        float g0 = f[0] + f[2];
        float g1 = f[1] + f[3];
        float dot = g0 + g1;

        float A = sz + cnorm[k];
        float d = fmaf(dot, -2.f, A);

        if (d < best) { best = d; bk = k; }
    }

    dcand[g * 64 + lane] = best;
    kcand[g * 64 + lane] = bk;
    __syncthreads();

    float bd = dcand[lane];
    int bi = kcand[lane];
    #pragma unroll
    for (int gg = 1; gg < 4; ++gg) {
        float d2 = dcand[gg * 64 + lane];
        int   k2 = kcand[gg * 64 + lane];
        if (d2 < bd) { bd = d2; bi = k2; }
    }

    if (g == 0) out[ZQ_ELEMS + n0 + lane] = (float)bi;

    const float* row = cb + (size_t)bi * CDIM;
    float* op = out + (size_t)b * CDIM * HW + hw0 + lane;
    #pragma unroll
    for (int c = 0; c < 16; ++c) {
        const int ch = g * 16 + c;
        op[(size_t)ch * HW] = row[ch];
    }
}

extern "C" void kernel_launch(void* const* d_in, const int* in_sizes, int n_in,
                              void* d_out, int out_size, void* d_ws, size_t ws_size,
                              hipStream_t stream) {
    const float* z_e = (const float*)d_in[0];
    const float* cb  = (const float*)d_in[1];
    float* out = (float*)d_out;

    float* cnorm_ws = nullptr;
    if (ws_size >= KCODES * sizeof(float)) {
        cnorm_ws = (float*)d_ws;
        cnorm_kernel<<<dim3(2), dim3(256), 0, stream>>>(cb, cnorm_ws);
    }

    // opt in to >64KB dynamic LDS (gfx950 allows up to 160KB/workgroup);
    // host-side metadata call, not a stream op (graph-capture safe)
    static int lds_ok = -1;
    if (lds_ok < 0) {
        lds_ok = (hipFuncSetAttribute((const void*)vq_lds,
                                      hipFuncAttributeMaxDynamicSharedMemorySize,
                                      LDS_BYTES) == hipSuccess) ? 1 : 0;
    }

    if (lds_ok == 1) {
        vq_lds<<<dim3(1024), dim3(512), LDS_BYTES, stream>>>(z_e, cb, cnorm_ws, out);
    } else {
        vq_sload<<<dim3(2048), dim3(256), 0, stream>>>(z_e, cb, cnorm_ws, out);
    }
}